// Round 1
// baseline (60.724 us; speedup 1.0000x reference)
//
#include <hip/hip_runtime.h>

#define B  32
#define H  56
#define Wd 56
#define C  256
#define HW (H*Wd)          // 3136
#define HWC (HW*C)         // 802816
#define CR 16              // C / ratio
#define NCHUNK 16
#define POS_PER_CHUNK (HW/NCHUNK)   // 196
#define ITERS (POS_PER_CHUNK/4)     // 49

// ---------------- Stage 1: partial spatial sums -> partial[b][chunk][c] ----
__global__ __launch_bounds__(256) void se_reduce(const float* __restrict__ in,
                                                 float* __restrict__ partial) {
    const int b     = blockIdx.x >> 4;     // NCHUNK == 16
    const int chunk = blockIdx.x & 15;
    const int t  = threadIdx.x;
    const int c4 = t & 63;                 // channel quad index (C/4 == 64)
    const int g  = t >> 6;                 // position group 0..3

    const float4* p = (const float4*)(in + (size_t)b * HWC
                                         + (size_t)(chunk * POS_PER_CHUNK + g) * C)
                      + c4;
    float4 acc = {0.f, 0.f, 0.f, 0.f};
    #pragma unroll 7
    for (int i = 0; i < ITERS; ++i) {
        float4 v = p[(size_t)i * 4 * (C/4)];   // step 4 positions * 64 float4/pos
        acc.x += v.x; acc.y += v.y; acc.z += v.z; acc.w += v.w;
    }

    __shared__ float4 red[256];
    red[t] = acc;
    __syncthreads();
    if (t < 64) {
        float4 a = red[t], b0 = red[t+64], c0 = red[t+128], d0 = red[t+192];
        float4 s;
        s.x = a.x + b0.x + c0.x + d0.x;
        s.y = a.y + b0.y + c0.y + d0.y;
        s.z = a.z + b0.z + c0.z + d0.z;
        s.w = a.w + b0.w + c0.w + d0.w;
        ((float4*)(partial + ((size_t)b * NCHUNK + chunk) * C))[t] = s;
    }
}

// ---------------- Stage 2: finish mean + 2-layer MLP -> exc[b][c] ----------
__global__ __launch_bounds__(256) void se_excite(const float* __restrict__ partial,
                                                 const float* __restrict__ W1,
                                                 const float* __restrict__ b1,
                                                 const float* __restrict__ W2,
                                                 const float* __restrict__ b2,
                                                 float* __restrict__ exc) {
    const int b = blockIdx.x;
    const int t = threadIdx.x;
    __shared__ float sq[C];
    __shared__ float h[CR];

    float s = 0.f;
    const float* pp = partial + (size_t)b * NCHUNK * C + t;
    #pragma unroll
    for (int k = 0; k < NCHUNK; ++k) s += pp[k * C];
    sq[t] = s * (1.0f / HW);
    __syncthreads();

    if (t < CR) {
        float acc = b1[t];
        #pragma unroll 8
        for (int c = 0; c < C; ++c) acc += sq[c] * W1[c * CR + t];
        h[t] = fmaxf(acc, 0.0f);
    }
    __syncthreads();

    float acc = b2[t];
    #pragma unroll
    for (int j = 0; j < CR; ++j) acc += h[j] * W2[j * C + t];
    exc[b * C + t] = 1.0f / (1.0f + expf(-acc));
}

// ---------------- Stage 3: out = in * exc[b][c] (broadcast) ----------------
__global__ __launch_bounds__(256) void se_scale(const float* __restrict__ in,
                                                const float* __restrict__ exc,
                                                float* __restrict__ out, int n4) {
    const int stride = gridDim.x * blockDim.x;
    const float4* in4  = (const float4*)in;
    const float4* exc4 = (const float4*)exc;
    float4* out4 = (float4*)out;
    for (int i = blockIdx.x * blockDim.x + threadIdx.x; i < n4; i += stride) {
        float4 v = in4[i];
        const int b  = i / (HWC/4);      // 200704
        const int c4 = i & 63;           // channel quad (C innermost)
        float4 e = exc4[(b << 6) + c4];
        v.x *= e.x; v.y *= e.y; v.z *= e.z; v.w *= e.w;
        out4[i] = v;
    }
}

extern "C" void kernel_launch(void* const* d_in, const int* in_sizes, int n_in,
                              void* d_out, int out_size, void* d_ws, size_t ws_size,
                              hipStream_t stream) {
    const float* in = (const float*)d_in[0];
    const float* W1 = (const float*)d_in[1];
    const float* b1 = (const float*)d_in[2];
    const float* W2 = (const float*)d_in[3];
    const float* b2 = (const float*)d_in[4];
    float* out = (float*)d_out;

    // Stage-1 partials live in d_out (fully overwritten by stage 3).
    float* partial = out;                  // 32*16*256 floats = 512 KB
    float* exc = (float*)d_ws;             // 32*256 floats = 32 KB

    se_reduce<<<B * NCHUNK, 256, 0, stream>>>(in, partial);
    se_excite<<<B, 256, 0, stream>>>(partial, W1, b1, W2, b2, exc);
    se_scale<<<2048, 256, 0, stream>>>(in, exc, out, (B * HWC) / 4);
}